// Round 1
// baseline (282.441 us; speedup 1.0000x reference)
//
#include <hip/hip_runtime.h>
#include <hip/hip_bf16.h>
#include <math.h>

#define BB 64
#define LL 2048
#define HH 512
#define EE 512
#define VV 32000
#define H3 1536

__device__ __forceinline__ void ld8(const float* __restrict__ p, float* v) {
  float4 a = *(const float4*)p;
  float4 b = *(const float4*)(p + 4);
  v[0]=a.x; v[1]=a.y; v[2]=a.z; v[3]=a.w;
  v[4]=b.x; v[5]=b.y; v[6]=b.z; v[7]=b.w;
}
__device__ __forceinline__ void ld16(const float* __restrict__ p, float* v) {
  ld8(p, v); ld8(p + 8, v + 8);
}
__device__ __forceinline__ float wsum(float v) {
#pragma unroll
  for (int off = 32; off; off >>= 1) v += __shfl_xor(v, off);
  return v;
}

// K1: gi = x @ W_ih^T + b_ih, gh = h @ W_hh^T + b_hh
// 1536 waves: wave = (j-pair, b-half). Each wave: 2 gate rows x 32 batches.
__global__ __launch_bounds__(256) void k1_gates(
    const int* __restrict__ seq, const float* __restrict__ h,
    const float* __restrict__ emb, const float* __restrict__ Wih,
    const float* __restrict__ Whh, const float* __restrict__ bih,
    const float* __restrict__ bhh, float* __restrict__ gi,
    float* __restrict__ gh) {
  int lane = threadIdx.x & 63;
  int wid = blockIdx.x * 4 + (threadIdx.x >> 6);  // 0..1535
  int jp = wid >> 1, bh = wid & 1;
  int j0 = jp * 2;
  float wih[2][8], whh[2][8];
#pragma unroll
  for (int r = 0; r < 2; ++r) {
    ld8(Wih + (size_t)(j0 + r) * EE + lane * 8, wih[r]);
    ld8(Whh + (size_t)(j0 + r) * HH + lane * 8, whh[r]);
  }
  for (int b = bh * 32; b < bh * 32 + 32; ++b) {
    int idx = seq[b];
    float xv[8], hv[8];
    ld8(emb + (size_t)idx * EE + lane * 8, xv);
    ld8(h + b * HH + lane * 8, hv);
#pragma unroll
    for (int r = 0; r < 2; ++r) {
      float di = 0.f, dh = 0.f;
#pragma unroll
      for (int i = 0; i < 8; ++i) {
        di += wih[r][i] * xv[i];
        dh += whh[r][i] * hv[i];
      }
      di = wsum(di);
      dh = wsum(dh);
      if (lane == 0) {
        gi[b * H3 + j0 + r] = di + bih[j0 + r];
        gh[b * H3 + j0 + r] = dh + bhh[j0 + r];
      }
    }
  }
}

// K2: GRU gate nonlinearity -> h_new. Also writes out1 and passthrough out3.
__global__ __launch_bounds__(256) void k2_hnew(
    const float* __restrict__ gi, const float* __restrict__ gh,
    const float* __restrict__ h, const float* __restrict__ feed,
    float* __restrict__ cat, float* __restrict__ out1,
    float* __restrict__ out3) {
  int t = blockIdx.x * 256 + threadIdx.x;  // 32768
  int b = t >> 9, k = t & 511;
  const float* gib = gi + b * H3;
  const float* ghb = gh + b * H3;
  float r = 1.f / (1.f + __expf(-(gib[k] + ghb[k])));
  float z = 1.f / (1.f + __expf(-(gib[k + HH] + ghb[k + HH])));
  float n = tanhf(gib[k + 2 * HH] + r * ghb[k + 2 * HH]);
  float hn = (1.f - z) * n + z * h[t];
  cat[b * 1024 + k] = hn;
  out1[t] = hn;
  out3[t] = feed[t];
}

// K3: fused scores + online-softmax partial context, one pass over enc.
// grid (16 chunks, 64 batches), 4 waves/block, each wave 32 rows of 128.
__global__ __launch_bounds__(256) void k3_attn(
    const float* __restrict__ enc, const float* __restrict__ cat,
    float* __restrict__ scores, float* __restrict__ pm,
    float* __restrict__ ps, float* __restrict__ pc) {
  int b = blockIdx.y, ch = blockIdx.x;
  int w = threadIdx.x >> 6, lane = threadIdx.x & 63;
  float hv[8];
  ld8(cat + b * 1024 + lane * 8, hv);
  float m = -INFINITY, s = 0.f, c[8];
#pragma unroll
  for (int j = 0; j < 8; ++j) c[j] = 0.f;
  const float* eb = enc + ((size_t)b * LL + ch * 128) * HH;
  for (int i = 0; i < 32; ++i) {
    int l = w + i * 4;
    float ev[8];
    ld8(eb + (size_t)l * HH + lane * 8, ev);
    float d = 0.f;
#pragma unroll
    for (int j = 0; j < 8; ++j) d += hv[j] * ev[j];
    d = wsum(d);
    if (lane == 0) scores[b * LL + ch * 128 + l] = d;
    if (d > m) {  // wave-uniform
      float sc = __expf(m - d);
      s *= sc;
#pragma unroll
      for (int j = 0; j < 8; ++j) c[j] *= sc;
      m = d;
    }
    float wgt = __expf(d - m);
    s += wgt;
#pragma unroll
    for (int j = 0; j < 8; ++j) c[j] += wgt * ev[j];
  }
  __shared__ float sm[4], ssum[4];
  __shared__ float scx[4][512];
  if (lane == 0) { sm[w] = m; ssum[w] = s; }
#pragma unroll
  for (int j = 0; j < 8; ++j) scx[w][lane * 8 + j] = c[j];
  __syncthreads();
  float mb = fmaxf(fmaxf(sm[0], sm[1]), fmaxf(sm[2], sm[3]));
  int t = threadIdx.x;
  if (t == 0) {
    float sb = 0.f;
#pragma unroll
    for (int w2 = 0; w2 < 4; ++w2) sb += ssum[w2] * __expf(sm[w2] - mb);
    pm[b * 16 + ch] = mb;
    ps[b * 16 + ch] = sb;
  }
  for (int k = t; k < 512; k += 256) {
    float v = 0.f;
#pragma unroll
    for (int w2 = 0; w2 < 4; ++w2) v += scx[w2][k] * __expf(sm[w2] - mb);
    pc[(size_t)(b * 16 + ch) * 512 + k] = v;
  }
}

// K4: cross-chunk combine -> context (into cat[:,512:]), save (max, denom).
__global__ __launch_bounds__(512) void k4_ctx(
    const float* __restrict__ pm, const float* __restrict__ ps,
    const float* __restrict__ pc, float* __restrict__ cat,
    float* __restrict__ mden) {
  int b = blockIdx.x;
  int k = threadIdx.x;  // 512
  float mb = -INFINITY;
#pragma unroll
  for (int ch = 0; ch < 16; ++ch) mb = fmaxf(mb, pm[b * 16 + ch]);
  float den = 0.f, v = 0.f;
#pragma unroll
  for (int ch = 0; ch < 16; ++ch) {
    float e = __expf(pm[b * 16 + ch] - mb);
    den += ps[b * 16 + ch] * e;
    v += pc[(size_t)(b * 16 + ch) * 512 + k] * e;
  }
  cat[b * 1024 + 512 + k] = v / den;
  if (k == 0) { mden[b * 2] = mb; mden[b * 2 + 1] = den; }
}

// K5: attn weights output = exp(score - m)/denom
__global__ __launch_bounds__(256) void k5_attnw(
    const float* __restrict__ scores, const float* __restrict__ mden,
    float* __restrict__ out2) {
  int t = blockIdx.x * 256 + threadIdx.x;  // 131072
  int b = t >> 11;
  out2[t] = __expf(scores[t] - mden[b * 2]) / mden[b * 2 + 1];
}

// K6: concat_output = tanh([h_new, ctx] @ W_concat^T + b_concat)
// 4096 waves: wave = (k-row, b-group of 8)
__global__ __launch_bounds__(256) void k6_concat(
    const float* __restrict__ cat, const float* __restrict__ Wc,
    const float* __restrict__ bc, float* __restrict__ co) {
  int lane = threadIdx.x & 63;
  int wid = blockIdx.x * 4 + (threadIdx.x >> 6);  // 0..4095
  int k = wid >> 3, bg = wid & 7;
  float wv[16];
  ld16(Wc + (size_t)k * 1024 + lane * 16, wv);
  float bk = bc[k];
  for (int b = bg * 8; b < bg * 8 + 8; ++b) {
    float cv[16];
    ld16(cat + b * 1024 + lane * 16, cv);
    float d = 0.f;
#pragma unroll
    for (int i = 0; i < 16; ++i) d += wv[i] * cv[i];
    d = wsum(d);
    if (lane == 0) co[b * HH + k] = tanhf(d + bk);
  }
}

// K7: output = concat_out @ W_out^T + b_out. lane = batch, wave = 16 v-cols.
__global__ __launch_bounds__(256) void k7_out(
    const float* __restrict__ co, const float* __restrict__ Wo,
    const float* __restrict__ bo, float* __restrict__ out0) {
  int lane = threadIdx.x & 63;
  int wid = blockIdx.x * 4 + (threadIdx.x >> 6);  // 0..1999
  wid = __builtin_amdgcn_readfirstlane(wid);
  int v0 = wid * 16;
  float acc[16];
#pragma unroll
  for (int i = 0; i < 16; ++i) acc[i] = 0.f;
  const float* crow = co + lane * HH;
  for (int k0 = 0; k0 < HH; k0 += 8) {
    float cv[8];
    ld8(crow + k0, cv);
#pragma unroll
    for (int i = 0; i < 16; ++i) {
      float wv[8];
      ld8(Wo + (size_t)(v0 + i) * HH + k0, wv);
#pragma unroll
      for (int j = 0; j < 8; ++j) acc[i] += cv[j] * wv[j];
    }
  }
  float* orow = out0 + (size_t)lane * VV + v0;
#pragma unroll
  for (int q = 0; q < 4; ++q) {
    float4 o;
    o.x = acc[4 * q + 0] + bo[v0 + 4 * q + 0];
    o.y = acc[4 * q + 1] + bo[v0 + 4 * q + 1];
    o.z = acc[4 * q + 2] + bo[v0 + 4 * q + 2];
    o.w = acc[4 * q + 3] + bo[v0 + 4 * q + 3];
    *(float4*)(orow + 4 * q) = o;
  }
}

extern "C" void kernel_launch(void* const* d_in, const int* in_sizes, int n_in,
                              void* d_out, int out_size, void* d_ws,
                              size_t ws_size, hipStream_t stream) {
  const int* seq = (const int*)d_in[0];
  const float* last_hidden = (const float*)d_in[1];
  const float* enc = (const float*)d_in[2];
  // d_in[3] encoder_labels unused
  const float* feed = (const float*)d_in[4];
  const float* emb = (const float*)d_in[5];
  const float* Wih = (const float*)d_in[6];
  const float* Whh = (const float*)d_in[7];
  const float* bih = (const float*)d_in[8];
  const float* bhh = (const float*)d_in[9];
  const float* Wc = (const float*)d_in[10];
  const float* bc = (const float*)d_in[11];
  const float* Wo = (const float*)d_in[12];
  const float* bo = (const float*)d_in[13];

  float* out = (float*)d_out;
  float* out0 = out;                  // B*V
  float* out1 = out + 2048000;        // B*H
  float* out2 = out + 2080768;        // B*L
  float* out3 = out + 2211840;        // B*H

  float* ws = (float*)d_ws;
  float* gi = ws;                 // 98304
  float* gh = gi + 98304;         // 98304
  float* cat = gh + 98304;        // 65536 (h_new | context)
  float* scores = cat + 65536;    // 131072
  float* pm = scores + 131072;    // 1024
  float* ps = pm + 1024;          // 1024
  float* pc = ps + 1024;          // 524288
  float* mden = pc + 524288;      // 128
  float* co = mden + 128;         // 32768

  hipLaunchKernelGGL(k1_gates, dim3(384), dim3(256), 0, stream,
                     seq, last_hidden, emb, Wih, Whh, bih, bhh, gi, gh);
  hipLaunchKernelGGL(k2_hnew, dim3(128), dim3(256), 0, stream,
                     gi, gh, last_hidden, feed, cat, out1, out3);
  hipLaunchKernelGGL(k3_attn, dim3(16, 64), dim3(256), 0, stream,
                     enc, cat, scores, pm, ps, pc);
  hipLaunchKernelGGL(k4_ctx, dim3(64), dim3(512), 0, stream,
                     pm, ps, pc, cat, mden);
  hipLaunchKernelGGL(k5_attnw, dim3(512), dim3(256), 0, stream,
                     scores, mden, out2);
  hipLaunchKernelGGL(k6_concat, dim3(1024), dim3(256), 0, stream,
                     cat, Wc, bc, co);
  hipLaunchKernelGGL(k7_out, dim3(500), dim3(256), 0, stream,
                     co, Wo, bo, out0);
}

// Round 3
// 178.966 us; speedup vs baseline: 1.5782x; 1.5782x over previous
//
#include <hip/hip_runtime.h>
#include <hip/hip_bf16.h>
#include <math.h>

#define BB 64
#define LL 2048
#define HH 512
#define EE 512
#define VV 32000
#define H3 1536

__device__ __forceinline__ void ld8(const float* __restrict__ p, float* v) {
  float4 a = *(const float4*)p;
  float4 b = *(const float4*)(p + 4);
  v[0]=a.x; v[1]=a.y; v[2]=a.z; v[3]=a.w;
  v[4]=b.x; v[5]=b.y; v[6]=b.z; v[7]=b.w;
}
__device__ __forceinline__ void ld16(const float* __restrict__ p, float* v) {
  ld8(p, v); ld8(p + 8, v + 8);
}
__device__ __forceinline__ void ld8s(const float* p, float* v) {
  float4 a = *(const float4*)p;
  float4 b = *(const float4*)(p + 4);
  v[0]=a.x; v[1]=a.y; v[2]=a.z; v[3]=a.w;
  v[4]=b.x; v[5]=b.y; v[6]=b.z; v[7]=b.w;
}
__device__ __forceinline__ float wsum(float v) {
#pragma unroll
  for (int off = 32; off; off >>= 1) v += __shfl_xor(v, off);
  return v;
}

// K1: gi = x @ W_ih^T + b_ih, gh = h @ W_hh^T + b_hh
__global__ __launch_bounds__(256) void k1_gates(
    const int* __restrict__ seq, const float* __restrict__ h,
    const float* __restrict__ emb, const float* __restrict__ Wih,
    const float* __restrict__ Whh, const float* __restrict__ bih,
    const float* __restrict__ bhh, float* __restrict__ gi,
    float* __restrict__ gh) {
  int lane = threadIdx.x & 63;
  int wid = blockIdx.x * 4 + (threadIdx.x >> 6);  // 0..1535
  int jp = wid >> 1, bh = wid & 1;
  int j0 = jp * 2;
  float wih[2][8], whh[2][8];
#pragma unroll
  for (int r = 0; r < 2; ++r) {
    ld8(Wih + (size_t)(j0 + r) * EE + lane * 8, wih[r]);
    ld8(Whh + (size_t)(j0 + r) * HH + lane * 8, whh[r]);
  }
  for (int b = bh * 32; b < bh * 32 + 32; ++b) {
    int idx = seq[b];
    float xv[8], hv[8];
    ld8(emb + (size_t)idx * EE + lane * 8, xv);
    ld8(h + b * HH + lane * 8, hv);
#pragma unroll
    for (int r = 0; r < 2; ++r) {
      float di = 0.f, dh = 0.f;
#pragma unroll
      for (int i = 0; i < 8; ++i) {
        di += wih[r][i] * xv[i];
        dh += whh[r][i] * hv[i];
      }
      di = wsum(di);
      dh = wsum(dh);
      if (lane == 0) {
        gi[b * H3 + j0 + r] = di + bih[j0 + r];
        gh[b * H3 + j0 + r] = dh + bhh[j0 + r];
      }
    }
  }
}

// K2: GRU gate nonlinearity -> h_new. Also writes out1 and passthrough out3.
__global__ __launch_bounds__(256) void k2_hnew(
    const float* __restrict__ gi, const float* __restrict__ gh,
    const float* __restrict__ h, const float* __restrict__ feed,
    float* __restrict__ cat, float* __restrict__ out1,
    float* __restrict__ out3) {
  int t = blockIdx.x * 256 + threadIdx.x;  // 32768
  int b = t >> 9, k = t & 511;
  const float* gib = gi + b * H3;
  const float* ghb = gh + b * H3;
  float r = 1.f / (1.f + __expf(-(gib[k] + ghb[k])));
  float z = 1.f / (1.f + __expf(-(gib[k + HH] + ghb[k + HH])));
  float n = tanhf(gib[k + 2 * HH] + r * ghb[k + 2 * HH]);
  float hn = (1.f - z) * n + z * h[t];
  cat[b * 1024 + k] = hn;
  out1[t] = hn;
  out3[t] = feed[t];
}

// K3: fused scores + online-softmax partial context, one pass over enc.
__global__ __launch_bounds__(256) void k3_attn(
    const float* __restrict__ enc, const float* __restrict__ cat,
    float* __restrict__ scores, float* __restrict__ pm,
    float* __restrict__ ps, float* __restrict__ pc) {
  int b = blockIdx.y, ch = blockIdx.x;
  int w = threadIdx.x >> 6, lane = threadIdx.x & 63;
  float hv[8];
  ld8(cat + b * 1024 + lane * 8, hv);
  float m = -INFINITY, s = 0.f, c[8];
#pragma unroll
  for (int j = 0; j < 8; ++j) c[j] = 0.f;
  const float* eb = enc + ((size_t)b * LL + ch * 128) * HH;
  for (int i = 0; i < 32; ++i) {
    int l = w + i * 4;
    float ev[8];
    ld8(eb + (size_t)l * HH + lane * 8, ev);
    float d = 0.f;
#pragma unroll
    for (int j = 0; j < 8; ++j) d += hv[j] * ev[j];
    d = wsum(d);
    if (lane == 0) scores[b * LL + ch * 128 + l] = d;
    if (d > m) {  // wave-uniform
      float sc = __expf(m - d);
      s *= sc;
#pragma unroll
      for (int j = 0; j < 8; ++j) c[j] *= sc;
      m = d;
    }
    float wgt = __expf(d - m);
    s += wgt;
#pragma unroll
    for (int j = 0; j < 8; ++j) c[j] += wgt * ev[j];
  }
  __shared__ float sm[4], ssum[4];
  __shared__ float scx[4][512];
  if (lane == 0) { sm[w] = m; ssum[w] = s; }
#pragma unroll
  for (int j = 0; j < 8; ++j) scx[w][lane * 8 + j] = c[j];
  __syncthreads();
  float mb = fmaxf(fmaxf(sm[0], sm[1]), fmaxf(sm[2], sm[3]));
  int t = threadIdx.x;
  if (t == 0) {
    float sb = 0.f;
#pragma unroll
    for (int w2 = 0; w2 < 4; ++w2) sb += ssum[w2] * __expf(sm[w2] - mb);
    pm[b * 16 + ch] = mb;
    ps[b * 16 + ch] = sb;
  }
  for (int k = t; k < 512; k += 256) {
    float v = 0.f;
#pragma unroll
    for (int w2 = 0; w2 < 4; ++w2) v += scx[w2][k] * __expf(sm[w2] - mb);
    pc[(size_t)(b * 16 + ch) * 512 + k] = v;
  }
}

// K4: cross-chunk combine -> context (into cat[:,512:]), save (max, denom).
__global__ __launch_bounds__(512) void k4_ctx(
    const float* __restrict__ pm, const float* __restrict__ ps,
    const float* __restrict__ pc, float* __restrict__ cat,
    float* __restrict__ mden) {
  int b = blockIdx.x;
  int k = threadIdx.x;  // 512
  float mb = -INFINITY;
#pragma unroll
  for (int ch = 0; ch < 16; ++ch) mb = fmaxf(mb, pm[b * 16 + ch]);
  float den = 0.f, v = 0.f;
#pragma unroll
  for (int ch = 0; ch < 16; ++ch) {
    float e = __expf(pm[b * 16 + ch] - mb);
    den += ps[b * 16 + ch] * e;
    v += pc[(size_t)(b * 16 + ch) * 512 + k] * e;
  }
  cat[b * 1024 + 512 + k] = v / den;
  if (k == 0) { mden[b * 2] = mb; mden[b * 2 + 1] = den; }
}

// K5: attn weights output = exp(score - m)/denom
__global__ __launch_bounds__(256) void k5_attnw(
    const float* __restrict__ scores, const float* __restrict__ mden,
    float* __restrict__ out2) {
  int t = blockIdx.x * 256 + threadIdx.x;  // 131072
  int b = t >> 11;
  out2[t] = __expf(scores[t] - mden[b * 2]) / mden[b * 2 + 1];
}

// K6: concat_output = tanh([h_new, ctx] @ W_concat^T + b_concat)
__global__ __launch_bounds__(256) void k6_concat(
    const float* __restrict__ cat, const float* __restrict__ Wc,
    const float* __restrict__ bc, float* __restrict__ co) {
  int lane = threadIdx.x & 63;
  int wid = blockIdx.x * 4 + (threadIdx.x >> 6);  // 0..4095
  int k = wid >> 3, bg = wid & 7;
  float wv[16];
  ld16(Wc + (size_t)k * 1024 + lane * 16, wv);
  float bk = bc[k];
  for (int b = bg * 8; b < bg * 8 + 8; ++b) {
    float cv[16];
    ld16(cat + b * 1024 + lane * 16, cv);
    float d = 0.f;
#pragma unroll
    for (int i = 0; i < 16; ++i) d += wv[i] * cv[i];
    d = wsum(d);
    if (lane == 0) co[b * HH + k] = tanhf(d + bk);
  }
}

// K7 v2: output = concat_out @ W_out^T + b_out.
// Block = 256 threads (4 waves), owns 32 vocab rows staged in LDS (64 KB).
// Wave w computes rows [w*8, w*8+8); lane = batch (coalesced writes).
// W_out streamed via coalesced float4 vector loads -> LDS; compute reads
// LDS with wave-uniform addresses (broadcast, conflict-free).
__global__ __launch_bounds__(256) void k7_out(
    const float* __restrict__ co, const float* __restrict__ Wo,
    const float* __restrict__ bo, float* __restrict__ out0) {
  __shared__ float sWo[32 * 512];  // 64 KB
  int t = threadIdx.x;
  int v0 = blockIdx.x * 32;
  // stage: 16384 floats = 4096 float4; 256 threads x 16 float4 each
  const float4* src = (const float4*)(Wo + (size_t)v0 * HH);
  float4* dst = (float4*)sWo;
#pragma unroll
  for (int i = 0; i < 16; ++i) {
    dst[t + i * 256] = src[t + i * 256];
  }
  __syncthreads();

  int w = t >> 6, lane = t & 63;
  int r0 = w * 8;  // first of 8 vocab rows for this wave
  float acc[8];
#pragma unroll
  for (int r = 0; r < 8; ++r) acc[r] = 0.f;
  const float* crow = co + lane * HH;
  for (int k0 = 0; k0 < HH; k0 += 8) {
    float cv[8];
    ld8(crow + k0, cv);
#pragma unroll
    for (int r = 0; r < 8; ++r) {
      float wv[8];
      ld8s(&sWo[(r0 + r) * 512 + k0], wv);
#pragma unroll
      for (int j = 0; j < 8; ++j) acc[r] += cv[j] * wv[j];
    }
  }
  float* orow = out0 + (size_t)lane * VV + v0 + r0;
#pragma unroll
  for (int q = 0; q < 2; ++q) {
    float4 o;
    o.x = acc[4 * q + 0] + bo[v0 + r0 + 4 * q + 0];
    o.y = acc[4 * q + 1] + bo[v0 + r0 + 4 * q + 1];
    o.z = acc[4 * q + 2] + bo[v0 + r0 + 4 * q + 2];
    o.w = acc[4 * q + 3] + bo[v0 + r0 + 4 * q + 3];
    *(float4*)(orow + 4 * q) = o;
  }
}

extern "C" void kernel_launch(void* const* d_in, const int* in_sizes, int n_in,
                              void* d_out, int out_size, void* d_ws,
                              size_t ws_size, hipStream_t stream) {
  const int* seq = (const int*)d_in[0];
  const float* last_hidden = (const float*)d_in[1];
  const float* enc = (const float*)d_in[2];
  // d_in[3] encoder_labels unused
  const float* feed = (const float*)d_in[4];
  const float* emb = (const float*)d_in[5];
  const float* Wih = (const float*)d_in[6];
  const float* Whh = (const float*)d_in[7];
  const float* bih = (const float*)d_in[8];
  const float* bhh = (const float*)d_in[9];
  const float* Wc = (const float*)d_in[10];
  const float* bc = (const float*)d_in[11];
  const float* Wo = (const float*)d_in[12];
  const float* bo = (const float*)d_in[13];

  float* out = (float*)d_out;
  float* out0 = out;                  // B*V
  float* out1 = out + 2048000;        // B*H
  float* out2 = out + 2080768;        // B*L
  float* out3 = out + 2211840;        // B*H

  float* ws = (float*)d_ws;
  float* gi = ws;                 // 98304
  float* gh = gi + 98304;         // 98304
  float* cat = gh + 98304;        // 65536 (h_new | context)
  float* scores = cat + 65536;    // 131072
  float* pm = scores + 131072;    // 1024
  float* ps = pm + 1024;          // 1024
  float* pc = ps + 1024;          // 524288
  float* mden = pc + 524288;      // 128
  float* co = mden + 128;         // 32768

  hipLaunchKernelGGL(k1_gates, dim3(384), dim3(256), 0, stream,
                     seq, last_hidden, emb, Wih, Whh, bih, bhh, gi, gh);
  hipLaunchKernelGGL(k2_hnew, dim3(128), dim3(256), 0, stream,
                     gi, gh, last_hidden, feed, cat, out1, out3);
  hipLaunchKernelGGL(k3_attn, dim3(16, 64), dim3(256), 0, stream,
                     enc, cat, scores, pm, ps, pc);
  hipLaunchKernelGGL(k4_ctx, dim3(64), dim3(512), 0, stream,
                     pm, ps, pc, cat, mden);
  hipLaunchKernelGGL(k5_attnw, dim3(512), dim3(256), 0, stream,
                     scores, mden, out2);
  hipLaunchKernelGGL(k6_concat, dim3(1024), dim3(256), 0, stream,
                     cat, Wc, bc, co);
  hipLaunchKernelGGL(k7_out, dim3(1000), dim3(256), 0, stream,
                     co, Wo, bo, out0);
}

// Round 4
// 133.512 us; speedup vs baseline: 2.1155x; 1.3404x over previous
//
#include <hip/hip_runtime.h>
#include <hip/hip_bf16.h>
#include <math.h>

#define BB 64
#define LL 2048
#define HH 512
#define EE 512
#define VV 32000
#define H3 1536

typedef __attribute__((ext_vector_type(8))) __bf16 bf16x8;
typedef __attribute__((ext_vector_type(4))) float f32x4;

__device__ __forceinline__ void ld8(const float* __restrict__ p, float* v) {
  float4 a = *(const float4*)p;
  float4 b = *(const float4*)(p + 4);
  v[0]=a.x; v[1]=a.y; v[2]=a.z; v[3]=a.w;
  v[4]=b.x; v[5]=b.y; v[6]=b.z; v[7]=b.w;
}
__device__ __forceinline__ void ld16(const float* __restrict__ p, float* v) {
  ld8(p, v); ld8(p + 8, v + 8);
}
__device__ __forceinline__ float wsum(float v) {
#pragma unroll
  for (int off = 32; off; off >>= 1) v += __shfl_xor(v, off);
  return v;
}
__device__ __forceinline__ unsigned short f2bf(float f) {
  unsigned int u = __float_as_uint(f);
  u = (u + 0x7FFFu + ((u >> 16) & 1u)) >> 16;
  return (unsigned short)u;
}

// K1: gi = x @ W_ih^T + b_ih, gh = h @ W_hh^T + b_hh
__global__ __launch_bounds__(256) void k1_gates(
    const int* __restrict__ seq, const float* __restrict__ h,
    const float* __restrict__ emb, const float* __restrict__ Wih,
    const float* __restrict__ Whh, const float* __restrict__ bih,
    const float* __restrict__ bhh, float* __restrict__ gi,
    float* __restrict__ gh) {
  int lane = threadIdx.x & 63;
  int wid = blockIdx.x * 4 + (threadIdx.x >> 6);  // 0..1535
  int jp = wid >> 1, bh = wid & 1;
  int j0 = jp * 2;
  float wih[2][8], whh[2][8];
#pragma unroll
  for (int r = 0; r < 2; ++r) {
    ld8(Wih + (size_t)(j0 + r) * EE + lane * 8, wih[r]);
    ld8(Whh + (size_t)(j0 + r) * HH + lane * 8, whh[r]);
  }
  for (int b = bh * 32; b < bh * 32 + 32; ++b) {
    int idx = seq[b];
    float xv[8], hv[8];
    ld8(emb + (size_t)idx * EE + lane * 8, xv);
    ld8(h + b * HH + lane * 8, hv);
#pragma unroll
    for (int r = 0; r < 2; ++r) {
      float di = 0.f, dh = 0.f;
#pragma unroll
      for (int i = 0; i < 8; ++i) {
        di += wih[r][i] * xv[i];
        dh += whh[r][i] * hv[i];
      }
      di = wsum(di);
      dh = wsum(dh);
      if (lane == 0) {
        gi[b * H3 + j0 + r] = di + bih[j0 + r];
        gh[b * H3 + j0 + r] = dh + bhh[j0 + r];
      }
    }
  }
}

// K2: GRU gate nonlinearity -> h_new. Also writes out1 and passthrough out3.
__global__ __launch_bounds__(256) void k2_hnew(
    const float* __restrict__ gi, const float* __restrict__ gh,
    const float* __restrict__ h, const float* __restrict__ feed,
    float* __restrict__ cat, float* __restrict__ out1,
    float* __restrict__ out3) {
  int t = blockIdx.x * 256 + threadIdx.x;  // 32768
  int b = t >> 9, k = t & 511;
  const float* gib = gi + b * H3;
  const float* ghb = gh + b * H3;
  float r = 1.f / (1.f + __expf(-(gib[k] + ghb[k])));
  float z = 1.f / (1.f + __expf(-(gib[k + HH] + ghb[k + HH])));
  float n = tanhf(gib[k + 2 * HH] + r * ghb[k + 2 * HH]);
  float hn = (1.f - z) * n + z * h[t];
  cat[b * 1024 + k] = hn;
  out1[t] = hn;
  out3[t] = feed[t];
}

// K3: fused scores + online-softmax partial context, one pass over enc.
__global__ __launch_bounds__(256) void k3_attn(
    const float* __restrict__ enc, const float* __restrict__ cat,
    float* __restrict__ scores, float* __restrict__ pm,
    float* __restrict__ ps, float* __restrict__ pc) {
  int b = blockIdx.y, ch = blockIdx.x;
  int w = threadIdx.x >> 6, lane = threadIdx.x & 63;
  float hv[8];
  ld8(cat + b * 1024 + lane * 8, hv);
  float m = -INFINITY, s = 0.f, c[8];
#pragma unroll
  for (int j = 0; j < 8; ++j) c[j] = 0.f;
  const float* eb = enc + ((size_t)b * LL + ch * 128) * HH;
  for (int i = 0; i < 32; ++i) {
    int l = w + i * 4;
    float ev[8];
    ld8(eb + (size_t)l * HH + lane * 8, ev);
    float d = 0.f;
#pragma unroll
    for (int j = 0; j < 8; ++j) d += hv[j] * ev[j];
    d = wsum(d);
    if (lane == 0) scores[b * LL + ch * 128 + l] = d;
    if (d > m) {  // wave-uniform
      float sc = __expf(m - d);
      s *= sc;
#pragma unroll
      for (int j = 0; j < 8; ++j) c[j] *= sc;
      m = d;
    }
    float wgt = __expf(d - m);
    s += wgt;
#pragma unroll
    for (int j = 0; j < 8; ++j) c[j] += wgt * ev[j];
  }
  __shared__ float sm[4], ssum[4];
  __shared__ float scx[4][512];
  if (lane == 0) { sm[w] = m; ssum[w] = s; }
#pragma unroll
  for (int j = 0; j < 8; ++j) scx[w][lane * 8 + j] = c[j];
  __syncthreads();
  float mb = fmaxf(fmaxf(sm[0], sm[1]), fmaxf(sm[2], sm[3]));
  int t = threadIdx.x;
  if (t == 0) {
    float sb = 0.f;
#pragma unroll
    for (int w2 = 0; w2 < 4; ++w2) sb += ssum[w2] * __expf(sm[w2] - mb);
    pm[b * 16 + ch] = mb;
    ps[b * 16 + ch] = sb;
  }
  for (int k = t; k < 512; k += 256) {
    float v = 0.f;
#pragma unroll
    for (int w2 = 0; w2 < 4; ++w2) v += scx[w2][k] * __expf(sm[w2] - mb);
    pc[(size_t)(b * 16 + ch) * 512 + k] = v;
  }
}

// K4: cross-chunk combine -> context (into cat[:,512:]), save (max, denom).
__global__ __launch_bounds__(512) void k4_ctx(
    const float* __restrict__ pm, const float* __restrict__ ps,
    const float* __restrict__ pc, float* __restrict__ cat,
    float* __restrict__ mden) {
  int b = blockIdx.x;
  int k = threadIdx.x;  // 512
  float mb = -INFINITY;
#pragma unroll
  for (int ch = 0; ch < 16; ++ch) mb = fmaxf(mb, pm[b * 16 + ch]);
  float den = 0.f, v = 0.f;
#pragma unroll
  for (int ch = 0; ch < 16; ++ch) {
    float e = __expf(pm[b * 16 + ch] - mb);
    den += ps[b * 16 + ch] * e;
    v += pc[(size_t)(b * 16 + ch) * 512 + k] * e;
  }
  cat[b * 1024 + 512 + k] = v / den;
  if (k == 0) { mden[b * 2] = mb; mden[b * 2 + 1] = den; }
}

// K5: attn weights output = exp(score - m)/denom
__global__ __launch_bounds__(256) void k5_attnw(
    const float* __restrict__ scores, const float* __restrict__ mden,
    float* __restrict__ out2) {
  int t = blockIdx.x * 256 + threadIdx.x;  // 131072
  int b = t >> 11;
  out2[t] = __expf(scores[t] - mden[b * 2]) / mden[b * 2 + 1];
}

// K6: concat_output = tanh([h_new, ctx] @ W_concat^T + b_concat) -> bf16
__global__ __launch_bounds__(256) void k6_concat(
    const float* __restrict__ cat, const float* __restrict__ Wc,
    const float* __restrict__ bc, unsigned short* __restrict__ co_bf) {
  int lane = threadIdx.x & 63;
  int wid = blockIdx.x * 4 + (threadIdx.x >> 6);  // 0..4095
  int k = wid >> 3, bg = wid & 7;
  float wv[16];
  ld16(Wc + (size_t)k * 1024 + lane * 16, wv);
  float bk = bc[k];
  for (int b = bg * 8; b < bg * 8 + 8; ++b) {
    float cv[16];
    ld16(cat + b * 1024 + lane * 16, cv);
    float d = 0.f;
#pragma unroll
    for (int i = 0; i < 16; ++i) d += wv[i] * cv[i];
    d = wsum(d);
    if (lane == 0) co_bf[b * HH + k] = f2bf(tanhf(d + bk));
  }
}

// K7 v3 (MFMA): out0 = co @ W_out^T + b_out, bf16 inputs / f32 accum.
// 500 blocks x 256 threads. Wave w: vocab rows [blk*64 + w*16, +16), all 64
// batches (4 batch-tiles). Per K-step of 32: B-frag from W_out f32 (global,
// cvt->bf16 in regs), 4 A-frags from bf16 co (L2). No LDS, no barriers.
// Frag maps: A[m=lane&15][k=(lane>>4)*8+i], B[k=(lane>>4)*8+i][n=lane&15],
// D row=(lane>>4)*4+reg (batch), col=lane&15 (vocab).
__global__ __launch_bounds__(256) void k7_out(
    const unsigned short* __restrict__ co_bf, const float* __restrict__ Wo,
    const float* __restrict__ bo, float* __restrict__ out0) {
  int t = threadIdx.x;
  int lane = t & 63, w = t >> 6;
  int v0 = blockIdx.x * 64 + w * 16;
  int l15 = lane & 15;
  int kbase = (lane >> 4) * 8;
  int vrow = v0 + l15;
  const float* wrow = Wo + (size_t)vrow * HH;

  f32x4 acc[4];
#pragma unroll
  for (int j = 0; j < 4; ++j) acc[j] = (f32x4){0.f, 0.f, 0.f, 0.f};

  for (int ks = 0; ks < HH; ks += 32) {
    int k = ks + kbase;
    float4 wa = *(const float4*)(wrow + k);
    float4 wb = *(const float4*)(wrow + k + 4);
    union { unsigned short u[8]; bf16x8 v; } B;
    B.u[0] = f2bf(wa.x); B.u[1] = f2bf(wa.y);
    B.u[2] = f2bf(wa.z); B.u[3] = f2bf(wa.w);
    B.u[4] = f2bf(wb.x); B.u[5] = f2bf(wb.y);
    B.u[6] = f2bf(wb.z); B.u[7] = f2bf(wb.w);
#pragma unroll
    for (int j = 0; j < 4; ++j) {
      bf16x8 A = *(const bf16x8*)(co_bf + (size_t)(j * 16 + l15) * HH + k);
      acc[j] = __builtin_amdgcn_mfma_f32_16x16x32_bf16(A, B.v, acc[j], 0, 0, 0);
    }
  }

  float bias = bo[vrow];
#pragma unroll
  for (int j = 0; j < 4; ++j) {
    int b0 = j * 16 + (lane >> 4) * 4;
#pragma unroll
    for (int r = 0; r < 4; ++r) {
      out0[(size_t)(b0 + r) * VV + vrow] = acc[j][r] + bias;
    }
  }
}

extern "C" void kernel_launch(void* const* d_in, const int* in_sizes, int n_in,
                              void* d_out, int out_size, void* d_ws,
                              size_t ws_size, hipStream_t stream) {
  const int* seq = (const int*)d_in[0];
  const float* last_hidden = (const float*)d_in[1];
  const float* enc = (const float*)d_in[2];
  // d_in[3] encoder_labels unused
  const float* feed = (const float*)d_in[4];
  const float* emb = (const float*)d_in[5];
  const float* Wih = (const float*)d_in[6];
  const float* Whh = (const float*)d_in[7];
  const float* bih = (const float*)d_in[8];
  const float* bhh = (const float*)d_in[9];
  const float* Wc = (const float*)d_in[10];
  const float* bc = (const float*)d_in[11];
  const float* Wo = (const float*)d_in[12];
  const float* bo = (const float*)d_in[13];

  float* out = (float*)d_out;
  float* out0 = out;                  // B*V
  float* out1 = out + 2048000;        // B*H
  float* out2 = out + 2080768;        // B*L
  float* out3 = out + 2211840;        // B*H

  float* ws = (float*)d_ws;
  float* gi = ws;                 // 98304
  float* gh = gi + 98304;         // 98304
  float* cat = gh + 98304;        // 65536 (h_new | context)
  float* scores = cat + 65536;    // 131072
  float* pm = scores + 131072;    // 1024
  float* ps = pm + 1024;          // 1024
  float* pc = ps + 1024;          // 524288
  float* mden = pc + 524288;      // 128
  unsigned short* co_bf = (unsigned short*)(mden + 128);  // 32768 ushort

  hipLaunchKernelGGL(k1_gates, dim3(384), dim3(256), 0, stream,
                     seq, last_hidden, emb, Wih, Whh, bih, bhh, gi, gh);
  hipLaunchKernelGGL(k2_hnew, dim3(128), dim3(256), 0, stream,
                     gi, gh, last_hidden, feed, cat, out1, out3);
  hipLaunchKernelGGL(k3_attn, dim3(16, 64), dim3(256), 0, stream,
                     enc, cat, scores, pm, ps, pc);
  hipLaunchKernelGGL(k4_ctx, dim3(64), dim3(512), 0, stream,
                     pm, ps, pc, cat, mden);
  hipLaunchKernelGGL(k5_attnw, dim3(512), dim3(256), 0, stream,
                     scores, mden, out2);
  hipLaunchKernelGGL(k6_concat, dim3(1024), dim3(256), 0, stream,
                     cat, Wc, bc, co_bf);
  hipLaunchKernelGGL(k7_out, dim3(500), dim3(256), 0, stream,
                     co_bf, Wo, bo, out0);
}